// Round 3
// baseline (168.676 us; speedup 1.0000x reference)
//
#include <hip/hip_runtime.h>

// Problem shape (fixed): B=8, C=21, H=512, W=512, fp32.
// Planes = B*C = 168, plane = 512*512 = 262144 floats = 65536 float4.
#define C_CLASSES 21
#define PLANE_F4 65536
#define N_PLANES 168
#define TOTAL_F4 ((long long)N_PLANES * PLANE_F4)  // 11,010,048
#define GRID 2048                                   // exactly 8 blocks/CU on 256 CUs
#define THREADS 256
#define F4_PER_BLOCK (TOTAL_F4 / GRID)              // 5376 (21 f4/thread)
#define DONE_IDX 63

// ws layout: uint32 ws[64]: [c*3 + {0,1,2}] = {pred_cnt, target_cnt, inter_cnt}
// for c in 0..20 (indices 0..62), ws[63] = block-done counter.
// Max count per class = 2,097,152 < 2^32.

__global__ __launch_bounds__(THREADS) void jaccard_count(
    const float4* __restrict__ p4,
    const float4* __restrict__ t4,
    unsigned int* __restrict__ ws,
    float* __restrict__ out) {
  __shared__ unsigned int s[3][THREADS / 64];
  __shared__ int is_last;

  const long long base = (long long)blockIdx.x * F4_PER_BLOCK;
  const long long end = base + F4_PER_BLOCK;
  // First plane boundary after base (plane = f4_idx >> 16).
  long long split = ((base >> 16) + 1) << 16;
  if (split > end) split = end;

  const int n0 = (int)(split - base);  // multiple of 256, > 0
  const int n1 = (int)(end - split);   // multiple of 256, >= 0

  // ---- segment 0 ----
  {
    const int c = (int)((base >> 16) % C_CLASSES);
    unsigned int pc = 0, tc = 0, ic = 0;
#pragma unroll 4
    for (int i = threadIdx.x; i < n0; i += THREADS) {
      const float4 p = p4[base + i];
      const float4 t = t4[base + i];
      unsigned pb, tb;
      pb = (p.x >= 0.5f); tb = (t.x == 1.0f); pc += pb; tc += tb; ic += pb & tb;
      pb = (p.y >= 0.5f); tb = (t.y == 1.0f); pc += pb; tc += tb; ic += pb & tb;
      pb = (p.z >= 0.5f); tb = (t.z == 1.0f); pc += pb; tc += tb; ic += pb & tb;
      pb = (p.w >= 0.5f); tb = (t.w == 1.0f); pc += pb; tc += tb; ic += pb & tb;
    }
#pragma unroll
    for (int off = 32; off > 0; off >>= 1) {
      pc += __shfl_down(pc, off, 64);
      tc += __shfl_down(tc, off, 64);
      ic += __shfl_down(ic, off, 64);
    }
    const int wave = threadIdx.x >> 6;
    if ((threadIdx.x & 63) == 0) { s[0][wave] = pc; s[1][wave] = tc; s[2][wave] = ic; }
    __syncthreads();
    if (threadIdx.x == 0) {
      unsigned int P = 0, T = 0, I = 0;
#pragma unroll
      for (int w = 0; w < THREADS / 64; ++w) { P += s[0][w]; T += s[1][w]; I += s[2][w]; }
      atomicAdd(&ws[c * 3 + 0], P);
      atomicAdd(&ws[c * 3 + 1], T);
      atomicAdd(&ws[c * 3 + 2], I);
    }
    __syncthreads();
  }

  // ---- segment 1 (crosses into next plane; often empty) ----
  if (n1 > 0) {
    const int c = (int)((split >> 16) % C_CLASSES);
    unsigned int pc = 0, tc = 0, ic = 0;
#pragma unroll 4
    for (int i = threadIdx.x; i < n1; i += THREADS) {
      const float4 p = p4[split + i];
      const float4 t = t4[split + i];
      unsigned pb, tb;
      pb = (p.x >= 0.5f); tb = (t.x == 1.0f); pc += pb; tc += tb; ic += pb & tb;
      pb = (p.y >= 0.5f); tb = (t.y == 1.0f); pc += pb; tc += tb; ic += pb & tb;
      pb = (p.z >= 0.5f); tb = (t.z == 1.0f); pc += pb; tc += tb; ic += pb & tb;
      pb = (p.w >= 0.5f); tb = (t.w == 1.0f); pc += pb; tc += tb; ic += pb & tb;
    }
#pragma unroll
    for (int off = 32; off > 0; off >>= 1) {
      pc += __shfl_down(pc, off, 64);
      tc += __shfl_down(tc, off, 64);
      ic += __shfl_down(ic, off, 64);
    }
    const int wave = threadIdx.x >> 6;
    if ((threadIdx.x & 63) == 0) { s[0][wave] = pc; s[1][wave] = tc; s[2][wave] = ic; }
    __syncthreads();
    if (threadIdx.x == 0) {
      unsigned int P = 0, T = 0, I = 0;
#pragma unroll
      for (int w = 0; w < THREADS / 64; ++w) { P += s[0][w]; T += s[1][w]; I += s[2][w]; }
      atomicAdd(&ws[c * 3 + 0], P);
      atomicAdd(&ws[c * 3 + 1], T);
      atomicAdd(&ws[c * 3 + 2], I);
    }
    __syncthreads();
  }

  // ---- fused finalize: last block to finish computes the output ----
  if (threadIdx.x == 0) {
    __threadfence();  // release: make our ws atomics visible before the ticket
    const unsigned int old = atomicAdd(&ws[DONE_IDX], 1u);
    is_last = (old == (unsigned int)(GRID - 1));
  }
  __syncthreads();
  if (is_last && threadIdx.x < C_CLASSES) {
    const int c = threadIdx.x;
    // Device-scope atomic reads (avoid stale per-XCD L2 lines).
    const float P = (float)atomicAdd(&ws[c * 3 + 0], 0u);
    const float T = (float)atomicAdd(&ws[c * 3 + 1], 0u);
    const float I = (float)atomicAdd(&ws[c * 3 + 2], 0u);
    const float U = P + T - I;
    out[c] = (U == 0.0f) ? __uint_as_float(0x7FC00000u) : I / fmaxf(U, 1.0f);
  }
}

extern "C" void kernel_launch(void* const* d_in, const int* in_sizes, int n_in,
                              void* d_out, int out_size, void* d_ws, size_t ws_size,
                              hipStream_t stream) {
  const float4* preds = (const float4*)d_in[0];
  const float4* target = (const float4*)d_in[1];
  unsigned int* ws = (unsigned int*)d_ws;
  float* out = (float*)d_out;

  hipMemsetAsync(ws, 0, 64 * sizeof(unsigned int), stream);
  jaccard_count<<<GRID, THREADS, 0, stream>>>(preds, target, ws, out);
}

// Round 4
// 77.676 us; speedup vs baseline: 2.1715x; 2.1715x over previous
//
#include <hip/hip_runtime.h>

// Problem shape (fixed): B=8, C=21, H=512, W=512, fp32.
// Total float4 = 8*21*512*512/4 = 11,010,048 = 2048 blocks * 21 groups * 256 lanes.
// A "group" = 256 contiguous float4 (one per thread). Plane = 256 groups, so a
// block's 21 consecutive groups cross at most ONE plane (class) boundary.
#define C_CLASSES 21
#define THREADS 256
#define GRID 2048   // exactly 8 blocks/CU on 256 CUs -> one uniform round, no tail
#define GROUPS 21

// ws: uint32 ws[63]: [c*3 + {0,1,2}] = {pred_cnt, target_cnt, inter_cnt}.
// Per-thread partial <= 84, per-wave <= 5376, per-block <= 21504 -> 16-bit
// packing (lo|hi<<16) is overflow-safe through the block reduction.

__global__ __launch_bounds__(THREADS) void jaccard_count(
    const float4* __restrict__ preds,
    const float4* __restrict__ target,
    unsigned int* __restrict__ ws) {
  const int first_g = blockIdx.x * GROUPS;      // 0..43007-20
  const int plane0 = first_g >> 8;              // 256 groups per plane
  int jsplit = ((plane0 + 1) << 8) - first_g;   // groups before next plane
  if (jsplit > GROUPS) jsplit = GROUPS;
  const int c0 = plane0 % C_CLASSES;
  const int c1 = (plane0 + 1) % C_CLASSES;      // used only if jsplit < GROUPS

  const float4* __restrict__ p = preds + ((long long)first_g << 8) + threadIdx.x;
  const float4* __restrict__ t = target + ((long long)first_g << 8) + threadIdx.x;

  unsigned int pc0 = 0, tc0 = 0, ic0 = 0;
  unsigned int pc1 = 0, tc1 = 0, ic1 = 0;
#pragma unroll
  for (int j = 0; j < GROUPS; ++j) {
    const float4 pv = p[j * 256];
    const float4 tv = t[j * 256];
    unsigned pb, tb, pcs = 0, tcs = 0, ics = 0;
    pb = (pv.x >= 0.5f); tb = (tv.x == 1.0f); pcs += pb; tcs += tb; ics += pb & tb;
    pb = (pv.y >= 0.5f); tb = (tv.y == 1.0f); pcs += pb; tcs += tb; ics += pb & tb;
    pb = (pv.z >= 0.5f); tb = (tv.z == 1.0f); pcs += pb; tcs += tb; ics += pb & tb;
    pb = (pv.w >= 0.5f); tb = (tv.w == 1.0f); pcs += pb; tcs += tb; ics += pb & tb;
    // Branchless class select (block-uniform, keeps accumulators in VGPRs).
    const unsigned m1 = (unsigned)-(int)(j >= jsplit);
    const unsigned m0 = ~m1;
    pc0 += pcs & m0; tc0 += tcs & m0; ic0 += ics & m0;
    pc1 += pcs & m1; tc1 += tcs & m1; ic1 += ics & m1;
  }

  // Pack to 3 reduction chains: (pc0|ic0<<16), (pc1|ic1<<16), (tc0|tc1<<16).
  unsigned a = pc0 | (ic0 << 16);
  unsigned b = pc1 | (ic1 << 16);
  unsigned d = tc0 | (tc1 << 16);
#pragma unroll
  for (int off = 32; off > 0; off >>= 1) {
    a += __shfl_down(a, off, 64);
    b += __shfl_down(b, off, 64);
    d += __shfl_down(d, off, 64);
  }

  __shared__ unsigned int s[3][THREADS / 64];
  const int wave = threadIdx.x >> 6;
  if ((threadIdx.x & 63) == 0) { s[0][wave] = a; s[1][wave] = b; s[2][wave] = d; }
  __syncthreads();
  if (threadIdx.x == 0) {
    unsigned A = 0, Bv = 0, D = 0;
#pragma unroll
    for (int w = 0; w < THREADS / 64; ++w) { A += s[0][w]; Bv += s[1][w]; D += s[2][w]; }
    atomicAdd(&ws[c0 * 3 + 0], A & 0xFFFFu);
    atomicAdd(&ws[c0 * 3 + 1], D & 0xFFFFu);
    atomicAdd(&ws[c0 * 3 + 2], A >> 16);
    if (jsplit < GROUPS) {
      atomicAdd(&ws[c1 * 3 + 0], Bv & 0xFFFFu);
      atomicAdd(&ws[c1 * 3 + 1], D >> 16);
      atomicAdd(&ws[c1 * 3 + 2], Bv >> 16);
    }
  }
}

__global__ void jaccard_finalize(const unsigned int* __restrict__ ws,
                                 float* __restrict__ out) {
  const int c = threadIdx.x;
  if (c < C_CLASSES) {
    const float P = (float)ws[c * 3 + 0];
    const float T = (float)ws[c * 3 + 1];
    const float I = (float)ws[c * 3 + 2];
    const float U = P + T - I;
    out[c] = (U == 0.0f) ? __uint_as_float(0x7FC00000u) : I / fmaxf(U, 1.0f);
  }
}

extern "C" void kernel_launch(void* const* d_in, const int* in_sizes, int n_in,
                              void* d_out, int out_size, void* d_ws, size_t ws_size,
                              hipStream_t stream) {
  const float4* preds = (const float4*)d_in[0];
  const float4* target = (const float4*)d_in[1];
  unsigned int* ws = (unsigned int*)d_ws;
  float* out = (float*)d_out;

  hipMemsetAsync(ws, 0, 64 * sizeof(unsigned int), stream);
  jaccard_count<<<GRID, THREADS, 0, stream>>>(preds, target, ws);
  jaccard_finalize<<<1, 64, 0, stream>>>(ws, out);
}

// Round 5
// 68.065 us; speedup vs baseline: 2.4782x; 1.1412x over previous
//
#include <hip/hip_runtime.h>

// Problem shape (fixed): B=8, C=21, H=512, W=512, fp32.
// Total float4 = 11,010,048 = 2048 blocks * 21 groups * 256 lanes.
// Plane = 256 groups => a block's 21 consecutive groups cross <= 1 class boundary.
#define C_CLASSES 21
#define THREADS 256
#define GRID 2048   // exactly 8 blocks/CU on 256 CUs -> one uniform round
#define GROUPS 21

// ws: uint4 ws[2048] per-block partial records (written unconditionally every
// call -> no zero-init needed, no memset node):
//   x = pc0 | tc0<<16,  y = ic0 | pc1<<16,  z = tc1 | ic1<<16,  w = c0 | c1<<8
// Per-block count <= 21*256*4 = 21504 < 2^16 -> 16-bit fields safe.

__global__ __launch_bounds__(THREADS) void jaccard_count(
    const float4* __restrict__ preds,
    const float4* __restrict__ target,
    uint4* __restrict__ ws) {
  const int first_g = blockIdx.x * GROUPS;
  const int plane0 = first_g >> 8;
  int jsplit = ((plane0 + 1) << 8) - first_g;
  if (jsplit > GROUPS) jsplit = GROUPS;
  const int c0 = plane0 % C_CLASSES;
  const int c1 = (plane0 + 1) % C_CLASSES;  // counts are 0 if no split

  const float4* __restrict__ p = preds + ((long long)first_g << 8) + threadIdx.x;
  const float4* __restrict__ t = target + ((long long)first_g << 8) + threadIdx.x;

  unsigned int pc0 = 0, tc0 = 0, ic0 = 0;
  unsigned int pc1 = 0, tc1 = 0, ic1 = 0;

#define PROC(J, PV, TV)                                                        \
  do {                                                                         \
    unsigned pb, tb, pcs = 0, tcs = 0, ics = 0;                                \
    pb = ((PV).x >= 0.5f); tb = ((TV).x == 1.0f); pcs += pb; tcs += tb; ics += pb & tb; \
    pb = ((PV).y >= 0.5f); tb = ((TV).y == 1.0f); pcs += pb; tcs += tb; ics += pb & tb; \
    pb = ((PV).z >= 0.5f); tb = ((TV).z == 1.0f); pcs += pb; tcs += tb; ics += pb & tb; \
    pb = ((PV).w >= 0.5f); tb = ((TV).w == 1.0f); pcs += pb; tcs += tb; ics += pb & tb; \
    const unsigned m1 = (unsigned)-(int)((J) >= jsplit);                       \
    const unsigned m0 = ~m1;                                                   \
    pc0 += pcs & m0; tc0 += tcs & m0; ic0 += ics & m0;                         \
    pc1 += pcs & m1; tc1 += tcs & m1; ic1 += ics & m1;                         \
  } while (0)

  // 7 batches of 3 groups: 6 x 16B loads in flight per thread (MLP depth 3).
#pragma unroll
  for (int jb = 0; jb < GROUPS; jb += 3) {
    const float4 pA = p[(jb + 0) * 256];
    const float4 tA = t[(jb + 0) * 256];
    const float4 pB = p[(jb + 1) * 256];
    const float4 tB = t[(jb + 1) * 256];
    const float4 pC = p[(jb + 2) * 256];
    const float4 tC = t[(jb + 2) * 256];
    PROC(jb + 0, pA, tA);
    PROC(jb + 1, pB, tB);
    PROC(jb + 2, pC, tC);
  }
#undef PROC

  // 3 packed reduction chains: (pc0|ic0<<16), (pc1|ic1<<16), (tc0|tc1<<16).
  unsigned a = pc0 | (ic0 << 16);
  unsigned b = pc1 | (ic1 << 16);
  unsigned d = tc0 | (tc1 << 16);
#pragma unroll
  for (int off = 32; off > 0; off >>= 1) {
    a += __shfl_down(a, off, 64);
    b += __shfl_down(b, off, 64);
    d += __shfl_down(d, off, 64);
  }

  __shared__ unsigned int s[3][THREADS / 64];
  const int wave = threadIdx.x >> 6;
  if ((threadIdx.x & 63) == 0) { s[0][wave] = a; s[1][wave] = b; s[2][wave] = d; }
  __syncthreads();
  if (threadIdx.x == 0) {
    unsigned A = 0, Bv = 0, D = 0;
#pragma unroll
    for (int w = 0; w < THREADS / 64; ++w) { A += s[0][w]; Bv += s[1][w]; D += s[2][w]; }
    uint4 rec;
    rec.x = (A & 0xFFFFu) | ((D & 0xFFFFu) << 16);   // pc0 | tc0<<16
    rec.y = (A >> 16) | ((Bv & 0xFFFFu) << 16);      // ic0 | pc1<<16
    rec.z = (D >> 16) | ((Bv >> 16) << 16);          // tc1 | ic1<<16
    rec.w = (unsigned)c0 | ((unsigned)c1 << 8);
    ws[blockIdx.x] = rec;
  }
}

__global__ __launch_bounds__(THREADS) void jaccard_finalize(
    const uint4* __restrict__ ws, float* __restrict__ out) {
  __shared__ unsigned int bins[C_CLASSES][3];
  if (threadIdx.x < C_CLASSES * 3) ((unsigned int*)bins)[threadIdx.x] = 0;
  __syncthreads();

#pragma unroll
  for (int r = 0; r < GRID / THREADS; ++r) {  // 8 records per thread
    const uint4 rec = ws[threadIdx.x + r * THREADS];
    const int c0 = rec.w & 0xFF;
    const int c1 = (rec.w >> 8) & 0xFF;
    atomicAdd(&bins[c0][0], rec.x & 0xFFFFu);
    atomicAdd(&bins[c0][1], rec.x >> 16);
    atomicAdd(&bins[c0][2], rec.y & 0xFFFFu);
    atomicAdd(&bins[c1][0], rec.y >> 16);
    atomicAdd(&bins[c1][1], rec.z & 0xFFFFu);
    atomicAdd(&bins[c1][2], rec.z >> 16);
  }
  __syncthreads();

  if (threadIdx.x < C_CLASSES) {
    const int c = threadIdx.x;
    const float P = (float)bins[c][0];
    const float T = (float)bins[c][1];
    const float I = (float)bins[c][2];
    const float U = P + T - I;
    out[c] = (U == 0.0f) ? __uint_as_float(0x7FC00000u) : I / fmaxf(U, 1.0f);
  }
}

extern "C" void kernel_launch(void* const* d_in, const int* in_sizes, int n_in,
                              void* d_out, int out_size, void* d_ws, size_t ws_size,
                              hipStream_t stream) {
  const float4* preds = (const float4*)d_in[0];
  const float4* target = (const float4*)d_in[1];
  uint4* ws = (uint4*)d_ws;  // 2048 * 16B = 32 KB
  float* out = (float*)d_out;

  jaccard_count<<<GRID, THREADS, 0, stream>>>(preds, target, ws);
  jaccard_finalize<<<1, THREADS, 0, stream>>>(ws, out);
}

// Round 6
// 59.935 us; speedup vs baseline: 2.8143x; 1.1356x over previous
//
#include <hip/hip_runtime.h>

// Problem shape (fixed): B=8, C=21, H=512, W=512, fp32.
// Total float4 = 11,010,048 = 2048 blocks * 21 groups * 256 lanes.
// Plane = 256 groups => a block's 21 consecutive groups cross <= 1 class boundary.
#define C_CLASSES 21
#define THREADS 256
#define GRID 2048   // exactly 8 blocks/CU on 256 CUs -> one uniform round
#define GROUPS 21

typedef float f32x4 __attribute__((ext_vector_type(4)));

// ws: uint4 ws[2048] per-block partial records (written unconditionally every
// call -> no zero-init needed, no memset node):
//   x = pc0 | tc0<<16,  y = ic0 | pc1<<16,  z = tc1 | ic1<<16,  w = c0 | c1<<8
// Per-block count <= 21*256*4 = 21504 < 2^16 -> 16-bit fields safe.

__global__ __launch_bounds__(THREADS) void jaccard_count(
    const f32x4* __restrict__ preds,
    const f32x4* __restrict__ target,
    uint4* __restrict__ ws) {
  const int first_g = blockIdx.x * GROUPS;
  const int plane0 = first_g >> 8;
  int jsplit = ((plane0 + 1) << 8) - first_g;
  if (jsplit > GROUPS) jsplit = GROUPS;
  const int c0 = plane0 % C_CLASSES;
  const int c1 = (plane0 + 1) % C_CLASSES;  // counts are 0 if no split

  const f32x4* __restrict__ p = preds + ((long long)first_g << 8) + threadIdx.x;
  const f32x4* __restrict__ t = target + ((long long)first_g << 8) + threadIdx.x;

  unsigned int pc0 = 0, tc0 = 0, ic0 = 0;
  unsigned int pc1 = 0, tc1 = 0, ic1 = 0;

#define PROC(J, PV, TV)                                                        \
  do {                                                                         \
    unsigned pb, tb, pcs = 0, tcs = 0, ics = 0;                                \
    pb = ((PV)[0] >= 0.5f); tb = ((TV)[0] == 1.0f); pcs += pb; tcs += tb; ics += pb & tb; \
    pb = ((PV)[1] >= 0.5f); tb = ((TV)[1] == 1.0f); pcs += pb; tcs += tb; ics += pb & tb; \
    pb = ((PV)[2] >= 0.5f); tb = ((TV)[2] == 1.0f); pcs += pb; tcs += tb; ics += pb & tb; \
    pb = ((PV)[3] >= 0.5f); tb = ((TV)[3] == 1.0f); pcs += pb; tcs += tb; ics += pb & tb; \
    const unsigned m1 = (unsigned)-(int)((J) >= jsplit);                       \
    const unsigned m0 = ~m1;                                                   \
    pc0 += pcs & m0; tc0 += tcs & m0; ic0 += ics & m0;                         \
    pc1 += pcs & m1; tc1 += tcs & m1; ic1 += ics & m1;                         \
  } while (0)

  // 7 batches of 3 groups; nontemporal (streaming) loads — zero reuse within
  // a pass, footprint (352MB) thrashes the 256MB L3.
#pragma unroll
  for (int jb = 0; jb < GROUPS; jb += 3) {
    const f32x4 pA = __builtin_nontemporal_load(p + (jb + 0) * 256);
    const f32x4 tA = __builtin_nontemporal_load(t + (jb + 0) * 256);
    const f32x4 pB = __builtin_nontemporal_load(p + (jb + 1) * 256);
    const f32x4 tB = __builtin_nontemporal_load(t + (jb + 1) * 256);
    const f32x4 pC = __builtin_nontemporal_load(p + (jb + 2) * 256);
    const f32x4 tC = __builtin_nontemporal_load(t + (jb + 2) * 256);
    PROC(jb + 0, pA, tA);
    PROC(jb + 1, pB, tB);
    PROC(jb + 2, pC, tC);
  }
#undef PROC

  // 3 packed reduction chains: (pc0|ic0<<16), (pc1|ic1<<16), (tc0|tc1<<16).
  unsigned a = pc0 | (ic0 << 16);
  unsigned b = pc1 | (ic1 << 16);
  unsigned d = tc0 | (tc1 << 16);
#pragma unroll
  for (int off = 32; off > 0; off >>= 1) {
    a += __shfl_down(a, off, 64);
    b += __shfl_down(b, off, 64);
    d += __shfl_down(d, off, 64);
  }

  __shared__ unsigned int s[3][THREADS / 64];
  const int wave = threadIdx.x >> 6;
  if ((threadIdx.x & 63) == 0) { s[0][wave] = a; s[1][wave] = b; s[2][wave] = d; }
  __syncthreads();
  if (threadIdx.x == 0) {
    unsigned A = 0, Bv = 0, D = 0;
#pragma unroll
    for (int w = 0; w < THREADS / 64; ++w) { A += s[0][w]; Bv += s[1][w]; D += s[2][w]; }
    uint4 rec;
    rec.x = (A & 0xFFFFu) | ((D & 0xFFFFu) << 16);   // pc0 | tc0<<16
    rec.y = (A >> 16) | ((Bv & 0xFFFFu) << 16);      // ic0 | pc1<<16
    rec.z = (D >> 16) | ((Bv >> 16) << 16);          // tc1 | ic1<<16
    rec.w = (unsigned)c0 | ((unsigned)c1 << 8);
    ws[blockIdx.x] = rec;
  }
}

__global__ __launch_bounds__(THREADS) void jaccard_finalize(
    const uint4* __restrict__ ws, float* __restrict__ out) {
  __shared__ unsigned int bins[C_CLASSES][3];
  if (threadIdx.x < C_CLASSES * 3) ((unsigned int*)bins)[threadIdx.x] = 0;
  __syncthreads();

#pragma unroll
  for (int r = 0; r < GRID / THREADS; ++r) {  // 8 records per thread
    const uint4 rec = ws[threadIdx.x + r * THREADS];
    const int c0 = rec.w & 0xFF;
    const int c1 = (rec.w >> 8) & 0xFF;
    atomicAdd(&bins[c0][0], rec.x & 0xFFFFu);
    atomicAdd(&bins[c0][1], rec.x >> 16);
    atomicAdd(&bins[c0][2], rec.y & 0xFFFFu);
    atomicAdd(&bins[c1][0], rec.y >> 16);
    atomicAdd(&bins[c1][1], rec.z & 0xFFFFu);
    atomicAdd(&bins[c1][2], rec.z >> 16);
  }
  __syncthreads();

  if (threadIdx.x < C_CLASSES) {
    const int c = threadIdx.x;
    const float P = (float)bins[c][0];
    const float T = (float)bins[c][1];
    const float I = (float)bins[c][2];
    const float U = P + T - I;
    out[c] = (U == 0.0f) ? __uint_as_float(0x7FC00000u) : I / fmaxf(U, 1.0f);
  }
}

extern "C" void kernel_launch(void* const* d_in, const int* in_sizes, int n_in,
                              void* d_out, int out_size, void* d_ws, size_t ws_size,
                              hipStream_t stream) {
  const f32x4* preds = (const f32x4*)d_in[0];
  const f32x4* target = (const f32x4*)d_in[1];
  uint4* ws = (uint4*)d_ws;  // 2048 * 16B = 32 KB
  float* out = (float*)d_out;

  jaccard_count<<<GRID, THREADS, 0, stream>>>(preds, target, ws);
  jaccard_finalize<<<1, THREADS, 0, stream>>>(ws, out);
}